// Round 2
// baseline (97256.909 us; speedup 1.0000x reference)
//
#include <hip/hip_runtime.h>

// ---------------------------------------------------------------------------
// 2-layer LSTM (S=4096, B=64, I=14, H=256) + ReLU + FC(256->1), eval mode.
// Persistent 2-stage pipelined scan: 8 workgroups total.
//   stage0 (blocks 0-3): layer0 scan, 16 chains/WG, K=288 (h256|x14|pad18)
//   stage1 (blocks 4-7): layer1 scan, K=512 (h1_256 | hs0_256), fused ReLU+FC
// W_ih1 GEMM folded into stage1's K-concat -> no pre1 ring, no fp32 handoff.
// Stage1 register-prefetches hs0[s+1] during step-s MFMA (stage0 runs ahead).
// f16 MFMA (16x16x32), fp32 accumulate + fp32 cell state + fp32 gate math.
// ---------------------------------------------------------------------------

#define S_LEN 4096
#define BATCH 64
#define IN_DIM 14
#define HID 256
#define GATES 1024
#define K0 288       // layer0 K (padded)
#define LDA0 296     // LDS A row stride (f16): 2-way bank alias only (free)
#define K1C 512      // layer1 concat K
#define LDA1 520     // (520*2/4)%32=4 -> 2-way alias only

typedef _Float16 half8 __attribute__((ext_vector_type(8)));
typedef float f32x4 __attribute__((ext_vector_type(4)));

__device__ __forceinline__ float sigf(float z) { return 1.0f / (1.0f + __expf(-z)); }
__device__ __forceinline__ float tanhf2(float z) { return 2.0f / (1.0f + __expf(-2.0f * z)) - 1.0f; }

__device__ __forceinline__ void wait_ge(int* p, int v) {
    while (__hip_atomic_load(p, __ATOMIC_ACQUIRE, __HIP_MEMORY_SCOPE_AGENT) < v)
        __builtin_amdgcn_s_sleep(2);
}
__device__ __forceinline__ void set_flag(int* p, int v) {
    __hip_atomic_store(p, v, __ATOMIC_RELEASE, __HIP_MEMORY_SCOPE_AGENT);
}

// ---------------------------------------------------------------------------
__global__ void prep_weights(const float* __restrict__ Wih0, const float* __restrict__ Whh0,
                             const float* __restrict__ bih0, const float* __restrict__ bhh0,
                             const float* __restrict__ Wih1, const float* __restrict__ Whh1,
                             const float* __restrict__ bih1, const float* __restrict__ bhh1,
                             _Float16* __restrict__ wcat0, _Float16* __restrict__ wcat1,
                             float* __restrict__ b0, float* __restrict__ b1) {
    int idx0 = blockIdx.x * blockDim.x + threadIdx.x;
    int stride = gridDim.x * blockDim.x;
    for (int i = idx0; i < GATES * K0; i += stride) {
        int n = i / K0, k = i % K0;
        float v = 0.f;
        if (k < HID) v = Whh0[n * HID + k];
        else if (k < HID + IN_DIM) v = Wih0[n * IN_DIM + (k - HID)];
        wcat0[i] = (_Float16)v;
    }
    for (int i = idx0; i < GATES * K1C; i += stride) {
        int n = i / K1C, k = i % K1C;
        float v = (k < HID) ? Whh1[n * HID + k] : Wih1[n * HID + (k - HID)];
        wcat1[i] = (_Float16)v;
    }
    for (int i = idx0; i < GATES; i += stride) {
        b0[i] = bih0[i] + bhh0[i];
        b1[i] = bih1[i] + bhh1[i];
    }
}

// ---------------------------------------------------------------------------
__global__ __launch_bounds__(512) void lstm_scan(
    const float* __restrict__ x, const float* __restrict__ h0, const float* __restrict__ c0,
    const _Float16* __restrict__ wcat0, const _Float16* __restrict__ wcat1,
    const float* __restrict__ b0, const float* __restrict__ b1,
    const float* __restrict__ wfc, const float* __restrict__ bfc,
    _Float16* __restrict__ hs0ring, int* __restrict__ flags, float* __restrict__ out,
    int R0) {
    const int stage = blockIdx.x >> 2;
    const int g = blockIdx.x & 3;
    const int tid = threadIdx.x;
    const int w = tid >> 6;          // wave 0..7
    const int lane = tid & 63;
    const int quad = lane >> 4;      // 0..3
    const int col = lane & 15;       // 0..15
    const int c0b = g * 16;          // chain base (global batch index)

    int* flag0  = flags + g * 64;          // stage0 produced h-layer0 up to step s
    int* flag1c = flags + 1024 + g * 64;   // stage1 consumed hs0 up to step s

    __shared__ __align__(16) _Float16 Ash[16 * LDA1];
    __shared__ float red[8][16];

    if (stage == 0) {
        // ---------------- layer0 scan ----------------
        {
            int m = tid >> 5, cw = tid & 31;
            const float* hp = h0 + (0 * BATCH + c0b + m) * HID + cw * 8;
            half8 hv;
#pragma unroll
            for (int j = 0; j < 8; ++j) hv[j] = (_Float16)hp[j];
            *(half8*)&Ash[m * LDA0 + cw * 8] = hv;
            if (cw >= IN_DIM) Ash[m * LDA0 + HID + cw] = (_Float16)0.f;
        }
        if (tid < 16 * IN_DIM) {
            int m = tid / IN_DIM, d = tid % IN_DIM;
            Ash[m * LDA0 + HID + d] = (_Float16)x[(0 * BATCH + c0b + m) * IN_DIM + d];
        }
        float bs[8];
#pragma unroll
        for (int a = 0; a < 8; ++a) bs[a] = b0[(w + 8 * a) * 16 + col];
        float cst[8];
#pragma unroll
        for (int a2 = 0; a2 < 2; ++a2)
#pragma unroll
            for (int r = 0; r < 4; ++r)
                cst[a2 * 4 + r] = c0[(0 * BATCH + c0b + quad * 4 + r) * HID + (w + 8 * a2) * 16 + col];
        const _Float16* wb = wcat0 + (w * 16 + col) * K0 + quad * 8;
        __syncthreads();

        for (int s = 0; s < S_LEN; ++s) {
            f32x4 acc[8];
#pragma unroll
            for (int a = 0; a < 8; ++a) acc[a] = (f32x4){bs[a], bs[a], bs[a], bs[a]};
            for (int kk = 0; kk < K0 / 32; ++kk) {
                half8 av = *(const half8*)&Ash[col * LDA0 + kk * 32 + quad * 8];
#pragma unroll
                for (int a = 0; a < 8; ++a) {
                    half8 bv = *(const half8*)(wb + a * (128 * K0) + kk * 32);
                    acc[a] = __builtin_amdgcn_mfma_f32_16x16x32_f16(av, bv, acc[a], 0, 0, 0);
                }
            }
            if (tid == 0 && s >= R0) wait_ge(flag1c, s - R0 + 1);  // ring guard
            __syncthreads();  // all A reads done; safe to overwrite

            int slot = s & (R0 - 1);
#pragma unroll
            for (int a2 = 0; a2 < 2; ++a2) {
                int j = (w + 8 * a2) * 16 + col;
#pragma unroll
                for (int r = 0; r < 4; ++r) {
                    int m = quad * 4 + r;
                    float iv = sigf(acc[0 + a2][r]);
                    float fv = sigf(acc[2 + a2][r]);
                    float gv = tanhf2(acc[4 + a2][r]);
                    float ov = sigf(acc[6 + a2][r]);
                    float c = fv * cst[a2 * 4 + r] + iv * gv;
                    cst[a2 * 4 + r] = c;
                    float hv = ov * tanhf2(c);
                    _Float16 hh = (_Float16)hv;
                    Ash[m * LDA0 + j] = hh;
                    hs0ring[(size_t)slot * (BATCH * HID) + (c0b + m) * HID + j] = hh;
                }
            }
            if (s + 1 < S_LEN && tid < 16 * IN_DIM) {
                int m = tid / IN_DIM, d = tid % IN_DIM;
                Ash[m * LDA0 + HID + d] = (_Float16)x[((s + 1) * BATCH + c0b + m) * IN_DIM + d];
            }
            __syncthreads();
            if (tid == 0) { __threadfence(); set_flag(flag0, s + 1); }
        }
    } else {
        // ---------------- layer1 scan (K=512 concat) + fused ReLU/FC --------
        const int m = tid >> 5, cw = tid & 31;
        {
            const float* hp = h0 + (1 * BATCH + c0b + m) * HID + cw * 8;
            half8 hv;
#pragma unroll
            for (int j = 0; j < 8; ++j) hv[j] = (_Float16)hp[j];
            *(half8*)&Ash[m * LDA1 + cw * 8] = hv;
        }
        float bs[8], cst[8], wf[2];
#pragma unroll
        for (int a = 0; a < 8; ++a) bs[a] = b1[(w + 8 * a) * 16 + col];
#pragma unroll
        for (int a2 = 0; a2 < 2; ++a2) {
            wf[a2] = wfc[(w + 8 * a2) * 16 + col];
#pragma unroll
            for (int r = 0; r < 4; ++r)
                cst[a2 * 4 + r] = c0[(1 * BATCH + c0b + quad * 4 + r) * HID + (w + 8 * a2) * 16 + col];
        }
        const float bfcv = bfc[0];
        const _Float16* wb = wcat1 + (w * 16 + col) * K1C + quad * 8;

        // initial fill: hs0[0] -> Ash cols [256,512)
        if (tid == 0) wait_ge(flag0, 1);
        __syncthreads();
        *(half8*)&Ash[m * LDA1 + HID + cw * 8] =
            *(const half8*)&hs0ring[(c0b + m) * HID + cw * 8];
        __syncthreads();

        for (int s = 0; s < S_LEN; ++s) {
            // Ash holds [h1[s-1] | hs0[s]]. Gate prefetch of hs0[s+1].
            if (s + 1 < S_LEN) {
                if (tid == 0) wait_ge(flag0, s + 2);
            }
            __syncthreads();
            half8 hpre = {};
            if (s + 1 < S_LEN)
                hpre = *(const half8*)&hs0ring[(size_t)((s + 1) & (R0 - 1)) * (BATCH * HID) +
                                               (c0b + m) * HID + cw * 8];

            f32x4 acc[8];
#pragma unroll
            for (int a = 0; a < 8; ++a) acc[a] = (f32x4){bs[a], bs[a], bs[a], bs[a]};
            for (int kk = 0; kk < K1C / 32; ++kk) {
                half8 av = *(const half8*)&Ash[col * LDA1 + kk * 32 + quad * 8];
#pragma unroll
                for (int a = 0; a < 8; ++a) {
                    half8 bv = *(const half8*)(wb + a * (128 * K1C) + kk * 32);
                    acc[a] = __builtin_amdgcn_mfma_f32_16x16x32_f16(av, bv, acc[a], 0, 0, 0);
                }
            }
            __syncthreads();  // all A reads done; Ash writable
            if (tid == 0) set_flag(flag1c, s);  // slot s consumed (s+1 still guarded)

            float part[4] = {0.f, 0.f, 0.f, 0.f};
#pragma unroll
            for (int a2 = 0; a2 < 2; ++a2) {
                int j = (w + 8 * a2) * 16 + col;
#pragma unroll
                for (int r = 0; r < 4; ++r) {
                    int mm = quad * 4 + r;
                    float iv = sigf(acc[0 + a2][r]);
                    float fv = sigf(acc[2 + a2][r]);
                    float gv = tanhf2(acc[4 + a2][r]);
                    float ov = sigf(acc[6 + a2][r]);
                    float c = fv * cst[a2 * 4 + r] + iv * gv;
                    cst[a2 * 4 + r] = c;
                    float hv = ov * tanhf2(c);
                    Ash[mm * LDA1 + j] = (_Float16)hv;
                    part[r] += fmaxf(hv, 0.f) * wf[a2];
                }
            }
            if (s + 1 < S_LEN)
                *(half8*)&Ash[m * LDA1 + HID + cw * 8] = hpre;  // stage next hs0

#pragma unroll
            for (int off = 1; off < 16; off <<= 1)
#pragma unroll
                for (int r = 0; r < 4; ++r) part[r] += __shfl_xor(part[r], off, 16);
            if (col == 0) {
#pragma unroll
                for (int r = 0; r < 4; ++r) red[w][quad * 4 + r] = part[r];
            }
            __syncthreads();
            if (tid < 16) {
                float t = bfcv;
#pragma unroll
                for (int ww = 0; ww < 8; ++ww) t += red[ww][tid];
                out[(size_t)s * BATCH + c0b + tid] = t;
            }
        }
    }
}

// ---------------------------------------------------------------------------
extern "C" void kernel_launch(void* const* d_in, const int* in_sizes, int n_in,
                              void* d_out, int out_size, void* d_ws, size_t ws_size,
                              hipStream_t stream) {
    const float* x    = (const float*)d_in[0];
    const float* h0   = (const float*)d_in[1];
    const float* c0   = (const float*)d_in[2];
    const float* Wih0 = (const float*)d_in[3];
    const float* Whh0 = (const float*)d_in[4];
    const float* bih0 = (const float*)d_in[5];
    const float* bhh0 = (const float*)d_in[6];
    const float* Wih1 = (const float*)d_in[7];
    const float* Whh1 = (const float*)d_in[8];
    const float* bih1 = (const float*)d_in[9];
    const float* bhh1 = (const float*)d_in[10];
    const float* Wfc  = (const float*)d_in[11];
    const float* bfc  = (const float*)d_in[12];
    float* out = (float*)d_out;

    char* ws = (char*)d_ws;
    constexpr size_t OFF_WCAT0 = 0;
    constexpr size_t SZ_WCAT0 = (size_t)GATES * K0 * 2;       // 576 KB
    constexpr size_t OFF_WCAT1 = OFF_WCAT0 + SZ_WCAT0;
    constexpr size_t SZ_WCAT1 = (size_t)GATES * K1C * 2;      // 1 MB
    constexpr size_t OFF_B0 = OFF_WCAT1 + SZ_WCAT1;
    constexpr size_t OFF_B1 = OFF_B0 + 4096;
    constexpr size_t OFF_FLAGS = OFF_B1 + 4096;
    constexpr size_t SZ_FLAGS = 16384;
    constexpr size_t OFF_RING = OFF_FLAGS + SZ_FLAGS;

    _Float16* wcat0 = (_Float16*)(ws + OFF_WCAT0);
    _Float16* wcat1 = (_Float16*)(ws + OFF_WCAT1);
    float* b0 = (float*)(ws + OFF_B0);
    float* b1 = (float*)(ws + OFF_B1);
    int* flags = (int*)(ws + OFF_FLAGS);

    int R0 = 128;  // hs0 slot = 32 KB (f16, whole batch)
    while (OFF_RING + (size_t)R0 * (BATCH * HID * 2) > ws_size && R0 > 8) R0 >>= 1;
    _Float16* hs0ring = (_Float16*)(ws + OFF_RING);

    hipMemsetAsync(flags, 0, SZ_FLAGS, stream);
    prep_weights<<<256, 256, 0, stream>>>(Wih0, Whh0, bih0, bhh0, Wih1, Whh1, bih1, bhh1,
                                          wcat0, wcat1, b0, b1);
    lstm_scan<<<8, 512, 0, stream>>>(x, h0, c0, wcat0, wcat1, b0, b1, Wfc, bfc,
                                     hs0ring, flags, out, R0);
}

// Round 3
// 20041.542 us; speedup vs baseline: 4.8528x; 4.8528x over previous
//
#include <hip/hip_runtime.h>

// ---------------------------------------------------------------------------
// 2-layer LSTM (S=4096, B=64, I=14, H=256) + ReLU + FC(256->1), eval mode.
// WEIGHT-STATIONARY gate-sliced design: 32 WGs (2 layers x 4 batch-groups x
// 4 gate-slices). Each WG owns 64 hidden units (=256 gate rows) of one layer
// for 16 batch chains and holds its weight slice ENTIRELY IN VGPRs
// (layer0: 72 VGPR/lane, layer1: 128 VGPR/lane). Zero weight traffic/step.
// Per step, WGs exchange 2KB f16 h-slices through L2 rings with
// release/acquire flags. Gate i/f/g/o combine routed through LDS (Gsh).
// FC fused into layer-1 WGs (slice j computes out rows 4j..4j+3 from the
// full h1[s-1] present in its A-buffer).
// ---------------------------------------------------------------------------

#define S_LEN 4096
#define BATCH 64
#define IN_DIM 14
#define HID 256
#define GATES 1024
#define K0 288        // layer0 K (h256 | x14 | pad18)
#define LDA0 296      // LDS A row stride (f16), layer0
#define K1 512        // layer1 K (h1 | hs0)
#define LDA1 520      // LDS A row stride (f16), layer1
#define GST 257       // gate LDS row stride (f32)
#define R1SLOTS 8     // h1 ring slots (lockstep peers, skew<=1)

typedef _Float16 half8 __attribute__((ext_vector_type(8)));
typedef float f32x4 __attribute__((ext_vector_type(4)));

__device__ __forceinline__ float sigf(float z) { return 1.0f / (1.0f + __expf(-z)); }
__device__ __forceinline__ float tanhf2(float z) { return 2.0f / (1.0f + __expf(-2.0f * z)) - 1.0f; }

__device__ __forceinline__ void wait_ge(int* p, int v) {
    while (__hip_atomic_load(p, __ATOMIC_ACQUIRE, __HIP_MEMORY_SCOPE_AGENT) < v)
        __builtin_amdgcn_s_sleep(2);
}
__device__ __forceinline__ void set_flag(int* p, int v) {
    __hip_atomic_store(p, v, __ATOMIC_RELEASE, __HIP_MEMORY_SCOPE_AGENT);
}

// ---------------------------------------------------------------------------
__global__ void prep_weights(const float* __restrict__ Wih0, const float* __restrict__ Whh0,
                             const float* __restrict__ bih0, const float* __restrict__ bhh0,
                             const float* __restrict__ Wih1, const float* __restrict__ Whh1,
                             const float* __restrict__ bih1, const float* __restrict__ bhh1,
                             _Float16* __restrict__ wcat0, _Float16* __restrict__ wcat1,
                             float* __restrict__ b0, float* __restrict__ b1) {
    int idx0 = blockIdx.x * blockDim.x + threadIdx.x;
    int stride = gridDim.x * blockDim.x;
    for (int i = idx0; i < GATES * K0; i += stride) {
        int n = i / K0, k = i % K0;
        float v = 0.f;
        if (k < HID) v = Whh0[n * HID + k];
        else if (k < HID + IN_DIM) v = Wih0[n * IN_DIM + (k - HID)];
        wcat0[i] = (_Float16)v;
    }
    for (int i = idx0; i < GATES * K1; i += stride) {
        int n = i / K1, k = i % K1;
        float v = (k < HID) ? Whh1[n * HID + k] : Wih1[n * HID + (k - HID)];
        wcat1[i] = (_Float16)v;
    }
    for (int i = idx0; i < GATES; i += stride) {
        b0[i] = bih0[i] + bhh0[i];
        b1[i] = bih1[i] + bhh1[i];
    }
}

// ---------------------------------------------------------------------------
__global__ __launch_bounds__(512) void lstm_scan(
    const float* __restrict__ x, const float* __restrict__ h0g, const float* __restrict__ c0g,
    const _Float16* __restrict__ wcat0, const _Float16* __restrict__ wcat1,
    const float* __restrict__ b0, const float* __restrict__ b1,
    const float* __restrict__ wfc, const float* __restrict__ bfc,
    _Float16* __restrict__ h0ring, _Float16* __restrict__ h1ring,
    int* __restrict__ flags, float* __restrict__ out, int R0) {
    // block decode: group g's 8 WGs at blockIdx in {2g,2g+1}+8k  (XCD heuristic)
    const int bi = blockIdx.x;
    const int x7 = bi & 7;
    const int g = x7 >> 1;                       // batch group 0..3
    const int sub = ((x7 & 1) << 2) | (bi >> 3); // 0..7
    const int L = sub >> 2;                      // layer
    const int j = sub & 3;                       // gate slice (64 units)

    const int tid = threadIdx.x;
    const int w = tid >> 6;        // wave 0..7
    const int lane = tid & 63;
    const int quad = lane >> 4;
    const int col = lane & 15;
    const int c0b = g * 16;        // batch base
    const int pm = tid & 15;       // pointwise row
    const int pu = (tid >> 4) * 2; // pointwise unit base (0..62, local)

    __shared__ __align__(16) _Float16 Ash[16 * LDA1];
    __shared__ float Gsh[16 * GST];
    __shared__ float WfS[HID];

    // flags (ints, stride 16): h0 slice published / h1 slice published / l1 progress
    int* my_h0f = flags + (g * 4 + j) * 16;
    int* my_h1f = flags + 1024 + (g * 4 + j) * 16;
    int* l1cp = flags + 2048 + g * 16;

    _Float16* h0rg = h0ring + (size_t)g * R0 * 4096;       // group ring base
    _Float16* h1rg = h1ring + (size_t)g * R1SLOTS * 4096;

    if (L == 0) {
        // ================= layer 0 (weights: 72 VGPR/lane) =================
        half8 wr[2][K0 / 32];
        float bs[2];
#pragma unroll
        for (int tt = 0; tt < 2; ++tt) {
            int t = w + 8 * tt;
            int n = (t >> 2) * 256 + j * 64 + (t & 3) * 16 + col;
            bs[tt] = b0[n];
            const _Float16* wp = wcat0 + (size_t)n * K0 + quad * 8;
#pragma unroll
            for (int kk = 0; kk < K0 / 32; ++kk) wr[tt][kk] = *(const half8*)(wp + kk * 32);
        }
        float cs0 = c0g[(size_t)(c0b + pm) * HID + j * 64 + pu];
        float cs1 = c0g[(size_t)(c0b + pm) * HID + j * 64 + pu + 1];
        // init A: h0(layer0) all cols + x[0] + pad
        {
            int m = tid >> 5, cw = tid & 31;
            const float* hp = h0g + (size_t)(c0b + m) * HID + cw * 8;
            half8 hv;
#pragma unroll
            for (int q2 = 0; q2 < 8; ++q2) hv[q2] = (_Float16)hp[q2];
            *(half8*)&Ash[m * LDA0 + cw * 8] = hv;
            if (cw >= IN_DIM) Ash[m * LDA0 + HID + cw] = (_Float16)0.f;
        }
        const int xm = tid / IN_DIM, xd = tid - xm * IN_DIM;  // for tid<224
        if (tid < 16 * IN_DIM)
            Ash[xm * LDA0 + HID + xd] = (_Float16)x[(size_t)(c0b + xm) * IN_DIM + xd];
        int* fpeer[3];
        {
            int c = 0;
            for (int p = 0; p < 4; ++p) if (p != j) fpeer[c++] = flags + (g * 4 + p) * 16;
        }
        __syncthreads();

        for (int s = 0; s < S_LEN; ++s) {
            // x[s+1] prefetch (independent of flags)
            float xpre = 0.f;
            if (tid < 16 * IN_DIM && s + 1 < S_LEN)
                xpre = x[((size_t)(s + 1) * BATCH + c0b + xm) * IN_DIM + xd];
            // polls: lanes 0..2 peers' h0[s-1]; lane 3 layer-1 progress guard
            if (w == 0) {
                if (lane < 3 && s > 0) wait_ge(fpeer[lane], s);
                if (lane == 3 && (s & 7) == 0 && s >= R0) wait_ge(l1cp, s - R0 + 12);
            }
            __syncthreads();
            // read peers' h0[s-1] slices into Ash
            if (s > 0 && tid < 384) {
                int m = tid & 15, rest = tid >> 4;
                int pp = rest >> 3; pp += (pp >= j);
                int ch = rest & 7;
                const _Float16* src = h0rg + (size_t)((s - 1) & (R0 - 1)) * 4096 +
                                      m * 256 + pp * 64 + ch * 8;
                *(half8*)&Ash[m * LDA0 + pp * 64 + ch * 8] = *(const half8*)src;
            }
            __syncthreads();
            // MFMA: gates slice = Wslice @ [h0[s-1]|x[s]]
            f32x4 acc0 = {bs[0], bs[0], bs[0], bs[0]};
            f32x4 acc1 = {bs[1], bs[1], bs[1], bs[1]};
#pragma unroll
            for (int kk = 0; kk < K0 / 32; ++kk) {
                half8 av = *(const half8*)&Ash[col * LDA0 + kk * 32 + quad * 8];
                acc0 = __builtin_amdgcn_mfma_f32_16x16x32_f16(av, wr[0][kk], acc0, 0, 0, 0);
                acc1 = __builtin_amdgcn_mfma_f32_16x16x32_f16(av, wr[1][kk], acc1, 0, 0, 0);
            }
#pragma unroll
            for (int r = 0; r < 4; ++r) {
                Gsh[(quad * 4 + r) * GST + w * 16 + col] = acc0[r];
                Gsh[(quad * 4 + r) * GST + (w + 8) * 16 + col] = acc1[r];
            }
            __syncthreads();
            // pointwise: 2 units per thread; h -> Ash own cols + ring
            {
                float iv = sigf(Gsh[pm * GST + pu]);
                float fv = sigf(Gsh[pm * GST + 64 + pu]);
                float gv = tanhf2(Gsh[pm * GST + 128 + pu]);
                float ov = sigf(Gsh[pm * GST + 192 + pu]);
                cs0 = fv * cs0 + iv * gv;
                float ha = ov * tanhf2(cs0);
                iv = sigf(Gsh[pm * GST + pu + 1]);
                fv = sigf(Gsh[pm * GST + 64 + pu + 1]);
                gv = tanhf2(Gsh[pm * GST + 128 + pu + 1]);
                ov = sigf(Gsh[pm * GST + 192 + pu + 1]);
                cs1 = fv * cs1 + iv * gv;
                float hb = ov * tanhf2(cs1);
                _Float16 fa = (_Float16)ha, fb = (_Float16)hb;
                Ash[pm * LDA0 + j * 64 + pu] = fa;
                Ash[pm * LDA0 + j * 64 + pu + 1] = fb;
                _Float16* rp = h0rg + (size_t)(s & (R0 - 1)) * 4096 + pm * 256 + j * 64 + pu;
                rp[0] = fa; rp[1] = fb;
            }
            if (tid < 16 * IN_DIM && s + 1 < S_LEN)
                Ash[xm * LDA0 + HID + xd] = (_Float16)xpre;
            __syncthreads();
            if (tid == 0) { __threadfence(); set_flag(my_h0f, s + 1); }
        }
    } else {
        // ================= layer 1 (weights: 128 VGPR/lane) + fused FC =====
        half8 wr[2][K1 / 32];
        float bs[2];
#pragma unroll
        for (int tt = 0; tt < 2; ++tt) {
            int t = w + 8 * tt;
            int n = (t >> 2) * 256 + j * 64 + (t & 3) * 16 + col;
            bs[tt] = b1[n];
            const _Float16* wp = wcat1 + (size_t)n * K1 + quad * 8;
#pragma unroll
            for (int kk = 0; kk < K1 / 32; ++kk) wr[tt][kk] = *(const half8*)(wp + kk * 32);
        }
        for (int i = tid; i < HID; i += 512) WfS[i] = wfc[i];
        const float bfcv = bfc[0];
        float cs0 = c0g[(size_t)(BATCH + c0b + pm) * HID + j * 64 + pu];
        float cs1 = c0g[(size_t)(BATCH + c0b + pm) * HID + j * 64 + pu + 1];
        {
            int m = tid >> 5, cw = tid & 31;
            const float* hp = h0g + (size_t)(BATCH + c0b + m) * HID + cw * 8;
            half8 hv;
#pragma unroll
            for (int q2 = 0; q2 < 8; ++q2) hv[q2] = (_Float16)hp[q2];
            *(half8*)&Ash[m * LDA1 + cw * 8] = hv;
        }
        int* fpeer[3];
        int* fh0s[4];
        {
            int c = 0;
            for (int p = 0; p < 4; ++p) {
                fh0s[p] = flags + (g * 4 + p) * 16;
                if (p != j) fpeer[c++] = flags + 1024 + (g * 4 + p) * 16;
            }
        }
        __syncthreads();

        for (int s = 0; s <= S_LEN; ++s) {
            // polls: lanes 0..2 -> h1 peers [s-1]; lanes 3..6 -> h0 slices [s]
            if (w == 0) {
                if (lane < 3 && s > 0) wait_ge(fpeer[lane], s);
                if (lane >= 3 && lane < 7 && s < S_LEN) wait_ge(fh0s[lane - 3], s + 1);
            }
            __syncthreads();
            // gather peers' h1[s-1] and h0[s]
            if (s > 0 && tid < 384) {
                int m = tid & 15, rest = tid >> 4;
                int pp = rest >> 3; pp += (pp >= j);
                int ch = rest & 7;
                const _Float16* src = h1rg + (size_t)((s - 1) & (R1SLOTS - 1)) * 4096 +
                                      m * 256 + pp * 64 + ch * 8;
                *(half8*)&Ash[m * LDA1 + pp * 64 + ch * 8] = *(const half8*)src;
            }
            if (s < S_LEN) {
                int m = tid & 15, rest = tid >> 4;
                int q2 = rest >> 3, ch = rest & 7;
                const _Float16* src = h0rg + (size_t)(s & (R0 - 1)) * 4096 +
                                      m * 256 + q2 * 64 + ch * 8;
                *(half8*)&Ash[m * LDA1 + HID + q2 * 64 + ch * 8] = *(const half8*)src;
            }
            __syncthreads();
            // fused FC on h1[s-1] (full vector now in Ash): rows 4j..4j+3, wave 7
            if (s > 0 && w == 7) {
                int m = 4 * j + quad;
                float fa = 0.f;
#pragma unroll
                for (int k16 = 0; k16 < 16; ++k16) {
                    float hv = (float)Ash[m * LDA1 + col + 16 * k16];
                    fa += fmaxf(hv, 0.f) * WfS[col + 16 * k16];
                }
#pragma unroll
                for (int off = 1; off < 16; off <<= 1) fa += __shfl_xor(fa, off, 16);
                if (col == 0) out[(size_t)(s - 1) * BATCH + c0b + m] = fa + bfcv;
            }
            if (s == S_LEN) break;
            // MFMA: gates slice = Wslice @ [h1[s-1]|hs0[s]]
            f32x4 acc0 = {bs[0], bs[0], bs[0], bs[0]};
            f32x4 acc1 = {bs[1], bs[1], bs[1], bs[1]};
#pragma unroll
            for (int kk = 0; kk < K1 / 32; ++kk) {
                half8 av = *(const half8*)&Ash[col * LDA1 + kk * 32 + quad * 8];
                acc0 = __builtin_amdgcn_mfma_f32_16x16x32_f16(av, wr[0][kk], acc0, 0, 0, 0);
                acc1 = __builtin_amdgcn_mfma_f32_16x16x32_f16(av, wr[1][kk], acc1, 0, 0, 0);
            }
#pragma unroll
            for (int r = 0; r < 4; ++r) {
                Gsh[(quad * 4 + r) * GST + w * 16 + col] = acc0[r];
                Gsh[(quad * 4 + r) * GST + (w + 8) * 16 + col] = acc1[r];
            }
            __syncthreads();
            {
                float iv = sigf(Gsh[pm * GST + pu]);
                float fv = sigf(Gsh[pm * GST + 64 + pu]);
                float gv = tanhf2(Gsh[pm * GST + 128 + pu]);
                float ov = sigf(Gsh[pm * GST + 192 + pu]);
                cs0 = fv * cs0 + iv * gv;
                float ha = ov * tanhf2(cs0);
                iv = sigf(Gsh[pm * GST + pu + 1]);
                fv = sigf(Gsh[pm * GST + 64 + pu + 1]);
                gv = tanhf2(Gsh[pm * GST + 128 + pu + 1]);
                ov = sigf(Gsh[pm * GST + 192 + pu + 1]);
                cs1 = fv * cs1 + iv * gv;
                float hb = ov * tanhf2(cs1);
                _Float16 fa = (_Float16)ha, fb = (_Float16)hb;
                Ash[pm * LDA1 + j * 64 + pu] = fa;
                Ash[pm * LDA1 + j * 64 + pu + 1] = fb;
                _Float16* rp = h1rg + (size_t)(s & (R1SLOTS - 1)) * 4096 + pm * 256 + j * 64 + pu;
                rp[0] = fa; rp[1] = fb;
            }
            __syncthreads();
            if (tid == 0) {
                __threadfence();
                set_flag(my_h1f, s + 1);
                if (j == 0 && (s & 7) == 7) set_flag(l1cp, s + 1);  // progress watermark
            }
        }
    }
}

// ---------------------------------------------------------------------------
extern "C" void kernel_launch(void* const* d_in, const int* in_sizes, int n_in,
                              void* d_out, int out_size, void* d_ws, size_t ws_size,
                              hipStream_t stream) {
    const float* x    = (const float*)d_in[0];
    const float* h0   = (const float*)d_in[1];
    const float* c0   = (const float*)d_in[2];
    const float* Wih0 = (const float*)d_in[3];
    const float* Whh0 = (const float*)d_in[4];
    const float* bih0 = (const float*)d_in[5];
    const float* bhh0 = (const float*)d_in[6];
    const float* Wih1 = (const float*)d_in[7];
    const float* Whh1 = (const float*)d_in[8];
    const float* bih1 = (const float*)d_in[9];
    const float* bhh1 = (const float*)d_in[10];
    const float* Wfc  = (const float*)d_in[11];
    const float* bfc  = (const float*)d_in[12];
    float* out = (float*)d_out;

    char* ws = (char*)d_ws;
    constexpr size_t OFF_WCAT0 = 0;
    constexpr size_t SZ_WCAT0 = (size_t)GATES * K0 * 2;   // 576 KB
    constexpr size_t OFF_WCAT1 = OFF_WCAT0 + SZ_WCAT0;
    constexpr size_t SZ_WCAT1 = (size_t)GATES * K1 * 2;   // 1 MB
    constexpr size_t OFF_B0 = OFF_WCAT1 + SZ_WCAT1;
    constexpr size_t OFF_B1 = OFF_B0 + 4096;
    constexpr size_t OFF_FLAGS = OFF_B1 + 4096;
    constexpr size_t SZ_FLAGS = 16384;
    constexpr size_t OFF_H1R = OFF_FLAGS + SZ_FLAGS;
    constexpr size_t SZ_H1R = (size_t)4 * R1SLOTS * 4096 * 2;  // 256 KB
    constexpr size_t OFF_H0R = OFF_H1R + SZ_H1R;

    _Float16* wcat0 = (_Float16*)(ws + OFF_WCAT0);
    _Float16* wcat1 = (_Float16*)(ws + OFF_WCAT1);
    float* b0 = (float*)(ws + OFF_B0);
    float* b1 = (float*)(ws + OFF_B1);
    int* flags = (int*)(ws + OFF_FLAGS);
    _Float16* h1ring = (_Float16*)(ws + OFF_H1R);

    int R0 = 256;  // h0 ring slots; per group slot = 8 KB
    while (OFF_H0R + (size_t)4 * R0 * 4096 * 2 > ws_size && R0 > 32) R0 >>= 1;
    _Float16* h0ring = (_Float16*)(ws + OFF_H0R);

    hipMemsetAsync(flags, 0, SZ_FLAGS, stream);
    prep_weights<<<256, 256, 0, stream>>>(Wih0, Whh0, bih0, bhh0, Wih1, Whh1, bih1, bhh1,
                                          wcat0, wcat1, b0, b1);
    lstm_scan<<<32, 512, 0, stream>>>(x, h0, c0, wcat0, wcat1, b0, b1, Wfc, bfc,
                                      h0ring, h1ring, flags, out, R0);
}

// Round 4
// 13814.742 us; speedup vs baseline: 7.0401x; 1.4507x over previous
//
#include <hip/hip_runtime.h>

// ---------------------------------------------------------------------------
// 2-layer LSTM (S=4096, B=64, I=14, H=256) + ReLU + FC(256->1), eval mode.
// WEIGHT-STATIONARY gate-sliced design: 32 WGs (2 layers x 4 batch-groups x
// 4 gate-slices), weights resident in VGPR/AGPR (L0: 72, L1: 128 regs/lane).
// R4: cross-WG exchange via TAGGED 64-bit relaxed agent atomics (sc1 ops,
// no threadfence / buffer_wbl2). Word = {h[2k]:f16, h[2k+1]:f16, tag:u32},
// tag = step+1. Consumers poll words in parallel, retry stragglers only.
// h1 ring depth 4 (lockstep skew<=1, no backpressure); h0 ring R0 slots with
// coarse consumed-watermark (1 relaxed word / 8 steps / consumer).
// ---------------------------------------------------------------------------

#define S_LEN 4096
#define BATCH 64
#define IN_DIM 14
#define HID 256
#define GATES 1024
#define K0 288        // layer0 K (h256 | x14 | pad18)
#define LDA0 296      // LDS A row stride (f16), layer0
#define K1 512        // layer1 K (h1 | hs0)
#define LDA1 520      // LDS A row stride (f16), layer1
#define GST 260       // gate LDS row stride (f32): 4*260%32=16 -> 2-way (free)

typedef _Float16 half8 __attribute__((ext_vector_type(8)));
typedef float f32x4 __attribute__((ext_vector_type(4)));
typedef unsigned long long u64;
typedef unsigned int u32;

__device__ __forceinline__ float sigf(float z) { return 1.0f / (1.0f + __expf(-z)); }
__device__ __forceinline__ float tanhf2(float z) { return 2.0f / (1.0f + __expf(-2.0f * z)) - 1.0f; }

__device__ __forceinline__ u64 aload(const u64* p) {
    return __hip_atomic_load(p, __ATOMIC_RELAXED, __HIP_MEMORY_SCOPE_AGENT);
}
__device__ __forceinline__ void astore(u64* p, u64 v) {
    __hip_atomic_store(p, v, __ATOMIC_RELAXED, __HIP_MEMORY_SCOPE_AGENT);
}
__device__ __forceinline__ int aloadi(const int* p) {
    return __hip_atomic_load(p, __ATOMIC_RELAXED, __HIP_MEMORY_SCOPE_AGENT);
}
__device__ __forceinline__ void astorei(int* p, int v) {
    __hip_atomic_store(p, v, __ATOMIC_RELAXED, __HIP_MEMORY_SCOPE_AGENT);
}
__device__ __forceinline__ u32 packh2(float a, float b) {
    union { _Float16 h[2]; u32 u; } q;
    q.h[0] = (_Float16)a; q.h[1] = (_Float16)b;
    return q.u;
}

// ---------------------------------------------------------------------------
__global__ void prep_weights(const float* __restrict__ Wih0, const float* __restrict__ Whh0,
                             const float* __restrict__ bih0, const float* __restrict__ bhh0,
                             const float* __restrict__ Wih1, const float* __restrict__ Whh1,
                             const float* __restrict__ bih1, const float* __restrict__ bhh1,
                             _Float16* __restrict__ wcat0, _Float16* __restrict__ wcat1,
                             float* __restrict__ b0, float* __restrict__ b1) {
    int idx0 = blockIdx.x * blockDim.x + threadIdx.x;
    int stride = gridDim.x * blockDim.x;
    for (int i = idx0; i < GATES * K0; i += stride) {
        int n = i / K0, k = i % K0;
        float v = 0.f;
        if (k < HID) v = Whh0[n * HID + k];
        else if (k < HID + IN_DIM) v = Wih0[n * IN_DIM + (k - HID)];
        wcat0[i] = (_Float16)v;
    }
    for (int i = idx0; i < GATES * K1; i += stride) {
        int n = i / K1, k = i % K1;
        float v = (k < HID) ? Whh1[n * HID + k] : Wih1[n * HID + (k - HID)];
        wcat1[i] = (_Float16)v;
    }
    for (int i = idx0; i < GATES; i += stride) {
        b0[i] = bih0[i] + bhh0[i];
        b1[i] = bih1[i] + bhh1[i];
    }
}

// ---------------------------------------------------------------------------
__global__ __launch_bounds__(512) void lstm_scan(
    const float* __restrict__ x, const float* __restrict__ h0g, const float* __restrict__ c0g,
    const _Float16* __restrict__ wcat0, const _Float16* __restrict__ wcat1,
    const float* __restrict__ b0, const float* __restrict__ b1,
    const float* __restrict__ wfc, const float* __restrict__ bfc,
    u64* __restrict__ h0ring, u64* __restrict__ h1ring,
    int* __restrict__ prog, float* __restrict__ out, int R0) {
    // block decode: group g's 8 WGs at blockIdx in {2g,2g+1}+8k (XCD heuristic)
    const int bi = blockIdx.x;
    const int x7 = bi & 7;
    const int g = x7 >> 1;                       // batch group 0..3
    const int sub = ((x7 & 1) << 2) | (bi >> 3); // 0..7
    const int L = sub >> 2;                      // layer
    const int j = sub & 3;                       // gate slice (64 units)

    const int tid = threadIdx.x;
    const int w = tid >> 6;        // wave 0..7
    const int lane = tid & 63;
    const int quad = lane >> 4;
    const int col = lane & 15;
    const int c0b = g * 16;        // batch base
    const int pm = tid & 15;       // pointwise chain
    const int iu = tid >> 4;       // pointwise unit-pair index (0..31)
    const int pu = iu * 2;         // pointwise unit base (0..62, local)
    const int gm = tid >> 5;       // gather chain (word idx = tid)
    const int gu = tid & 31;       // gather unit-pair

    __shared__ __align__(16) _Float16 Ash[16 * LDA1];
    __shared__ float Gsh[16 * GST];
    __shared__ float WfS[HID];

    u64* h0w = h0ring + (size_t)g * R0 * 2048;  // [slot][slice 4][512 words]
    u64* h1w = h1ring + (size_t)g * 4 * 2048;
    const int R0m = R0 - 1;

    int peer[3];
    { int c = 0; for (int p = 0; p < 4; ++p) if (p != j) peer[c++] = p; }

    if (L == 0) {
        // ================= layer 0 (weights: 72 regs/lane) =================
        half8 wr[2][K0 / 32];
        float bs[2];
#pragma unroll
        for (int tt = 0; tt < 2; ++tt) {
            int t = w + 8 * tt;
            int n = (t >> 2) * 256 + j * 64 + (t & 3) * 16 + col;
            bs[tt] = b0[n];
            const _Float16* wp = wcat0 + (size_t)n * K0 + quad * 8;
#pragma unroll
            for (int kk = 0; kk < K0 / 32; ++kk) wr[tt][kk] = *(const half8*)(wp + kk * 32);
        }
        float cs0 = c0g[(size_t)(c0b + pm) * HID + j * 64 + pu];
        float cs1 = c0g[(size_t)(c0b + pm) * HID + j * 64 + pu + 1];
        {
            int m = tid >> 5, cw = tid & 31;
            const float* hp = h0g + (size_t)(c0b + m) * HID + cw * 8;
            half8 hv;
#pragma unroll
            for (int q2 = 0; q2 < 8; ++q2) hv[q2] = (_Float16)hp[q2];
            *(half8*)&Ash[m * LDA0 + cw * 8] = hv;
            if (cw >= IN_DIM) Ash[m * LDA0 + HID + cw] = (_Float16)0.f;
        }
        const int xm = tid / IN_DIM, xd = tid - xm * IN_DIM;  // for tid<224
        if (tid < 16 * IN_DIM)
            Ash[xm * LDA0 + HID + xd] = (_Float16)x[(size_t)(c0b + xm) * IN_DIM + xd];
        int* progw = prog + g * 4;
        __syncthreads();

        for (int s = 0; s < S_LEN; ++s) {
            float xpre = 0.f;
            if (tid < 16 * IN_DIM && s + 1 < S_LEN)
                xpre = x[((size_t)(s + 1) * BATCH + c0b + xm) * IN_DIM + xd];
            // gather peers' h0[s-1] (tagged words, parallel poll)
            if (s > 0) {
                const u64* base = h0w + (size_t)((s - 1) & R0m) * 2048;
                const u64* ap[3];
                u64 pv[3];
#pragma unroll
                for (int i = 0; i < 3; ++i) ap[i] = base + peer[i] * 512 + tid;
#pragma unroll
                for (int i = 0; i < 3; ++i) pv[i] = aload(ap[i]);
                for (;;) {
                    bool any = false;
#pragma unroll
                    for (int i = 0; i < 3; ++i)
                        if ((u32)(pv[i] >> 32) != (u32)s) { any = true; pv[i] = aload(ap[i]); }
                    if (!any) break;
                    __builtin_amdgcn_s_sleep(1);
                }
#pragma unroll
                for (int i = 0; i < 3; ++i)
                    *(u32*)&Ash[gm * LDA0 + peer[i] * 64 + 2 * gu] = (u32)pv[i];
            }
            // coarse backpressure vs layer-1 consumers (every 8 steps)
            if (w == 0 && lane < 4 && (s & 7) == 0 && s >= R0 - 8) {
                int need = s + 8 - R0;
                while (aloadi(progw + lane) < need) __builtin_amdgcn_s_sleep(16);
            }
            __syncthreads();
            // MFMA: gates slice = Wslice @ [h0[s-1]|x[s]]
            f32x4 acc0 = {bs[0], bs[0], bs[0], bs[0]};
            f32x4 acc1 = {bs[1], bs[1], bs[1], bs[1]};
#pragma unroll
            for (int kk = 0; kk < K0 / 32; ++kk) {
                half8 av = *(const half8*)&Ash[col * LDA0 + kk * 32 + quad * 8];
                acc0 = __builtin_amdgcn_mfma_f32_16x16x32_f16(av, wr[0][kk], acc0, 0, 0, 0);
                acc1 = __builtin_amdgcn_mfma_f32_16x16x32_f16(av, wr[1][kk], acc1, 0, 0, 0);
            }
#pragma unroll
            for (int r = 0; r < 4; ++r) {
                Gsh[(quad * 4 + r) * GST + w * 16 + col] = acc0[r];
                Gsh[(quad * 4 + r) * GST + (w + 8) * 16 + col] = acc1[r];
            }
            __syncthreads();
            // pointwise: 2 units/thread; h -> own Ash cols + tagged publish
            {
                float iv = sigf(Gsh[pm * GST + pu]);
                float fv = sigf(Gsh[pm * GST + 64 + pu]);
                float gv = tanhf2(Gsh[pm * GST + 128 + pu]);
                float ov = sigf(Gsh[pm * GST + 192 + pu]);
                cs0 = fv * cs0 + iv * gv;
                float ha = ov * tanhf2(cs0);
                iv = sigf(Gsh[pm * GST + pu + 1]);
                fv = sigf(Gsh[pm * GST + 64 + pu + 1]);
                gv = tanhf2(Gsh[pm * GST + 128 + pu + 1]);
                ov = sigf(Gsh[pm * GST + 192 + pu + 1]);
                cs1 = fv * cs1 + iv * gv;
                float hb = ov * tanhf2(cs1);
                u32 hw = packh2(ha, hb);
                *(u32*)&Ash[pm * LDA0 + j * 64 + pu] = hw;
                astore(h0w + (size_t)(s & R0m) * 2048 + j * 512 + (pm * 32 + iu),
                       (u64)hw | ((u64)(u32)(s + 1) << 32));
            }
            if (tid < 16 * IN_DIM && s + 1 < S_LEN)
                Ash[xm * LDA0 + HID + xd] = (_Float16)xpre;
            __syncthreads();
        }
    } else {
        // ================= layer 1 (weights: 128 regs/lane) + fused FC =====
        half8 wr[2][K1 / 32];
        float bs[2];
#pragma unroll
        for (int tt = 0; tt < 2; ++tt) {
            int t = w + 8 * tt;
            int n = (t >> 2) * 256 + j * 64 + (t & 3) * 16 + col;
            bs[tt] = b1[n];
            const _Float16* wp = wcat1 + (size_t)n * K1 + quad * 8;
#pragma unroll
            for (int kk = 0; kk < K1 / 32; ++kk) wr[tt][kk] = *(const half8*)(wp + kk * 32);
        }
        for (int i = tid; i < HID; i += 512) WfS[i] = wfc[i];
        const float bfcv = bfc[0];
        float cs0 = c0g[(size_t)(BATCH + c0b + pm) * HID + j * 64 + pu];
        float cs1 = c0g[(size_t)(BATCH + c0b + pm) * HID + j * 64 + pu + 1];
        {
            int m = tid >> 5, cw = tid & 31;
            const float* hp = h0g + (size_t)(BATCH + c0b + m) * HID + cw * 8;
            half8 hv;
#pragma unroll
            for (int q2 = 0; q2 < 8; ++q2) hv[q2] = (_Float16)hp[q2];
            *(half8*)&Ash[m * LDA1 + cw * 8] = hv;
        }
        int* progself = prog + g * 4 + j;
        __syncthreads();

        for (int s = 0; s <= S_LEN; ++s) {
            const bool gp = (s > 0), gh = (s < S_LEN);
            const u64* ap[7];
            u32 wt[7];
            bool act[7];
            u64 vv[7];
            {
                const u64* b1p = h1w + (size_t)((s - 1) & 3) * 2048;
                const u64* b0p = h0w + (size_t)(s & R0m) * 2048;
#pragma unroll
                for (int i = 0; i < 3; ++i) {
                    act[i] = gp; ap[i] = b1p + peer[i] * 512 + tid; wt[i] = (u32)s;
                }
#pragma unroll
                for (int p = 0; p < 4; ++p) {
                    act[3 + p] = gh; ap[3 + p] = b0p + p * 512 + tid; wt[3 + p] = (u32)(s + 1);
                }
            }
#pragma unroll
            for (int i = 0; i < 7; ++i) vv[i] = act[i] ? aload(ap[i]) : 0;
            for (;;) {
                bool any = false;
#pragma unroll
                for (int i = 0; i < 7; ++i)
                    if (act[i] && (u32)(vv[i] >> 32) != wt[i]) { any = true; vv[i] = aload(ap[i]); }
                if (!any) break;
                __builtin_amdgcn_s_sleep(1);
            }
            if (gp) {
#pragma unroll
                for (int i = 0; i < 3; ++i)
                    *(u32*)&Ash[gm * LDA1 + peer[i] * 64 + 2 * gu] = (u32)vv[i];
            }
            if (gh) {
#pragma unroll
                for (int p = 0; p < 4; ++p)
                    *(u32*)&Ash[gm * LDA1 + HID + p * 64 + 2 * gu] = (u32)vv[3 + p];
            }
            __syncthreads();
            // fused FC on h1[s-1] (full vector in Ash cols 0..255): wave 7
            if (s > 0 && w == 7) {
                int m = 4 * j + quad;
                float fa = 0.f;
#pragma unroll
                for (int k16 = 0; k16 < 16; ++k16) {
                    float hv = (float)Ash[m * LDA1 + col + 16 * k16];
                    fa += fmaxf(hv, 0.f) * WfS[col + 16 * k16];
                }
#pragma unroll
                for (int off = 1; off < 16; off <<= 1) fa += __shfl_xor(fa, off, 16);
                if (col == 0) out[(size_t)(s - 1) * BATCH + c0b + m] = fa + bfcv;
            }
            if (s == S_LEN) break;
            // MFMA: gates slice = Wslice @ [h1[s-1]|hs0[s]]
            f32x4 acc0 = {bs[0], bs[0], bs[0], bs[0]};
            f32x4 acc1 = {bs[1], bs[1], bs[1], bs[1]};
#pragma unroll
            for (int kk = 0; kk < K1 / 32; ++kk) {
                half8 av = *(const half8*)&Ash[col * LDA1 + kk * 32 + quad * 8];
                acc0 = __builtin_amdgcn_mfma_f32_16x16x32_f16(av, wr[0][kk], acc0, 0, 0, 0);
                acc1 = __builtin_amdgcn_mfma_f32_16x16x32_f16(av, wr[1][kk], acc1, 0, 0, 0);
            }
#pragma unroll
            for (int r = 0; r < 4; ++r) {
                Gsh[(quad * 4 + r) * GST + w * 16 + col] = acc0[r];
                Gsh[(quad * 4 + r) * GST + (w + 8) * 16 + col] = acc1[r];
            }
            __syncthreads();
            {
                float iv = sigf(Gsh[pm * GST + pu]);
                float fv = sigf(Gsh[pm * GST + 64 + pu]);
                float gv = tanhf2(Gsh[pm * GST + 128 + pu]);
                float ov = sigf(Gsh[pm * GST + 192 + pu]);
                cs0 = fv * cs0 + iv * gv;
                float ha = ov * tanhf2(cs0);
                iv = sigf(Gsh[pm * GST + pu + 1]);
                fv = sigf(Gsh[pm * GST + 64 + pu + 1]);
                gv = tanhf2(Gsh[pm * GST + 128 + pu + 1]);
                ov = sigf(Gsh[pm * GST + 192 + pu + 1]);
                cs1 = fv * cs1 + iv * gv;
                float hb = ov * tanhf2(cs1);
                u32 hw = packh2(ha, hb);
                *(u32*)&Ash[pm * LDA1 + j * 64 + pu] = hw;
                astore(h1w + (size_t)(s & 3) * 2048 + j * 512 + (pm * 32 + iu),
                       (u64)hw | ((u64)(u32)(s + 1) << 32));
            }
            if ((s & 7) == 7 && tid == 0) astorei(progself, s + 1);
            __syncthreads();
        }
    }
}

// ---------------------------------------------------------------------------
extern "C" void kernel_launch(void* const* d_in, const int* in_sizes, int n_in,
                              void* d_out, int out_size, void* d_ws, size_t ws_size,
                              hipStream_t stream) {
    const float* x    = (const float*)d_in[0];
    const float* h0   = (const float*)d_in[1];
    const float* c0   = (const float*)d_in[2];
    const float* Wih0 = (const float*)d_in[3];
    const float* Whh0 = (const float*)d_in[4];
    const float* bih0 = (const float*)d_in[5];
    const float* bhh0 = (const float*)d_in[6];
    const float* Wih1 = (const float*)d_in[7];
    const float* Whh1 = (const float*)d_in[8];
    const float* bih1 = (const float*)d_in[9];
    const float* bhh1 = (const float*)d_in[10];
    const float* Wfc  = (const float*)d_in[11];
    const float* bfc  = (const float*)d_in[12];
    float* out = (float*)d_out;

    char* ws = (char*)d_ws;
    constexpr size_t OFF_WCAT0 = 0;
    constexpr size_t SZ_WCAT0 = (size_t)GATES * K0 * 2;   // 576 KB
    constexpr size_t OFF_WCAT1 = OFF_WCAT0 + SZ_WCAT0;
    constexpr size_t SZ_WCAT1 = (size_t)GATES * K1 * 2;   // 1 MB
    constexpr size_t OFF_B0 = OFF_WCAT1 + SZ_WCAT1;
    constexpr size_t OFF_B1 = OFF_B0 + 4096;
    constexpr size_t OFF_PROG = OFF_B1 + 4096;
    constexpr size_t SZ_PROG = 16384;
    constexpr size_t OFF_H1R = OFF_PROG + SZ_PROG;
    constexpr size_t SZ_H1R = (size_t)4 * 4 * 2048 * 8;   // 256 KB
    constexpr size_t OFF_H0R = OFF_H1R + SZ_H1R;

    _Float16* wcat0 = (_Float16*)(ws + OFF_WCAT0);
    _Float16* wcat1 = (_Float16*)(ws + OFF_WCAT1);
    float* b0 = (float*)(ws + OFF_B0);
    float* b1 = (float*)(ws + OFF_B1);
    int* prog = (int*)(ws + OFF_PROG);
    u64* h1ring = (u64*)(ws + OFF_H1R);

    int R0 = 128;  // h0 ring slots; per group slot = 16 KB (tagged words)
    while (OFF_H0R + (size_t)4 * R0 * 2048 * 8 > ws_size && R0 > 16) R0 >>= 1;
    u64* h0ring = (u64*)(ws + OFF_H0R);

    hipMemsetAsync(prog, 0, SZ_PROG, stream);
    prep_weights<<<256, 256, 0, stream>>>(Wih0, Whh0, bih0, bhh0, Wih1, Whh1, bih1, bhh1,
                                          wcat0, wcat1, b0, b1);
    lstm_scan<<<32, 512, 0, stream>>>(x, h0, c0, wcat0, wcat1, b0, b1, Wfc, bfc,
                                      h0ring, h1ring, prog, out, R0);
}

// Round 5
// 11682.969 us; speedup vs baseline: 8.3247x; 1.1825x over previous
//
#include <hip/hip_runtime.h>

// ---------------------------------------------------------------------------
// 2-layer LSTM (S=4096, B=64, I=14, H=256) + ReLU + FC(256->1), eval mode.
// WEIGHT-STATIONARY gate-sliced design: 32 WGs (2 layers x 4 batch-groups x
// 4 gate-slices), weights resident in VGPR/AGPR.
// R5 handshake redesign:
//  - producers: per-wave notify counter posted AFTER `s_waitcnt vmcnt(0)`
//    (publish stores acked at coherence point before notify is visible).
//  - consumers: wave0 polls only notify words (224 B/round vs 28 KB/round);
//    data gathered once (speculative issue + tag-validate + rare reload).
//  - L1: h0[s+1] register-prefetched during step s (L0 runs ahead);
//    FC hidden under the notify poll on wave 7 (OwnH defers own-slice Ash
//    update so Ash stays a coherent snapshot of h1[s-1] for the FC).
// ---------------------------------------------------------------------------

#define S_LEN 4096
#define BATCH 64
#define IN_DIM 14
#define HID 256
#define GATES 1024
#define K0 288        // layer0 K (h256 | x14 | pad18)
#define LDA0 296      // LDS A row stride (f16), layer0
#define K1 512        // layer1 K (h1 | hs0)
#define LDA1 520      // LDS A row stride (f16), layer1
#define GST 260       // gate LDS row stride (f32): 2-way only (free)

#define NFY(L, g, j, wv) ((((((L)*4 + (g)) * 4 + (j)) * 8) + (wv)) * 16)

typedef _Float16 half8 __attribute__((ext_vector_type(8)));
typedef float f32x4 __attribute__((ext_vector_type(4)));
typedef unsigned long long u64;
typedef unsigned int u32;

__device__ __forceinline__ float sigf(float z) { return 1.0f / (1.0f + __expf(-z)); }
__device__ __forceinline__ float tanhf2(float z) { return 2.0f / (1.0f + __expf(-2.0f * z)) - 1.0f; }

__device__ __forceinline__ u64 aload(const u64* p) {
    return __hip_atomic_load(p, __ATOMIC_RELAXED, __HIP_MEMORY_SCOPE_AGENT);
}
__device__ __forceinline__ void astore(u64* p, u64 v) {
    __hip_atomic_store(p, v, __ATOMIC_RELAXED, __HIP_MEMORY_SCOPE_AGENT);
}
__device__ __forceinline__ u32 aload32(const u32* p) {
    return __hip_atomic_load(p, __ATOMIC_RELAXED, __HIP_MEMORY_SCOPE_AGENT);
}
__device__ __forceinline__ void astore32(u32* p, u32 v) {
    __hip_atomic_store(p, v, __ATOMIC_RELAXED, __HIP_MEMORY_SCOPE_AGENT);
}
__device__ __forceinline__ u32 packh2(float a, float b) {
    union { _Float16 h[2]; u32 u; } q;
    q.h[0] = (_Float16)a; q.h[1] = (_Float16)b;
    return q.u;
}

// ---------------------------------------------------------------------------
__global__ void prep_weights(const float* __restrict__ Wih0, const float* __restrict__ Whh0,
                             const float* __restrict__ bih0, const float* __restrict__ bhh0,
                             const float* __restrict__ Wih1, const float* __restrict__ Whh1,
                             const float* __restrict__ bih1, const float* __restrict__ bhh1,
                             _Float16* __restrict__ wcat0, _Float16* __restrict__ wcat1,
                             float* __restrict__ b0, float* __restrict__ b1) {
    int idx0 = blockIdx.x * blockDim.x + threadIdx.x;
    int stride = gridDim.x * blockDim.x;
    for (int i = idx0; i < GATES * K0; i += stride) {
        int n = i / K0, k = i % K0;
        float v = 0.f;
        if (k < HID) v = Whh0[n * HID + k];
        else if (k < HID + IN_DIM) v = Wih0[n * IN_DIM + (k - HID)];
        wcat0[i] = (_Float16)v;
    }
    for (int i = idx0; i < GATES * K1; i += stride) {
        int n = i / K1, k = i % K1;
        float v = (k < HID) ? Whh1[n * HID + k] : Wih1[n * HID + (k - HID)];
        wcat1[i] = (_Float16)v;
    }
    for (int i = idx0; i < GATES; i += stride) {
        b0[i] = bih0[i] + bhh0[i];
        b1[i] = bih1[i] + bhh1[i];
    }
}

// ---------------------------------------------------------------------------
__global__ __launch_bounds__(512) void lstm_scan(
    const float* __restrict__ x, const float* __restrict__ h0g, const float* __restrict__ c0g,
    const _Float16* __restrict__ wcat0, const _Float16* __restrict__ wcat1,
    const float* __restrict__ b0, const float* __restrict__ b1,
    const float* __restrict__ wfc, const float* __restrict__ bfc,
    u64* __restrict__ h0ring, u64* __restrict__ h1ring,
    u32* __restrict__ nfy, u32* __restrict__ prog, float* __restrict__ out, int R0) {
    // block decode: group g's 8 WGs at blockIdx in {2g,2g+1}+8k (XCD heuristic)
    const int bi = blockIdx.x;
    const int x7 = bi & 7;
    const int g = x7 >> 1;                       // batch group 0..3
    const int sub = ((x7 & 1) << 2) | (bi >> 3); // 0..7
    const int L = sub >> 2;                      // layer
    const int j = sub & 3;                       // gate slice (64 units)

    const int tid = threadIdx.x;
    const int w = tid >> 6;        // wave 0..7
    const int lane = tid & 63;
    const int quad = lane >> 4;
    const int col = lane & 15;
    const int c0b = g * 16;        // batch base
    const int pm = tid & 15;       // pointwise chain
    const int iu = tid >> 4;       // pointwise unit-pair index (0..31)
    const int pu = iu * 2;         // pointwise unit base (0..62, local)
    const int gm = tid >> 5;       // gather chain (word idx = tid)
    const int gu = tid & 31;       // gather unit-pair

    __shared__ __align__(16) _Float16 Ash[16 * LDA1];
    __shared__ float Gsh[16 * GST];
    __shared__ float WfS[HID];
    __shared__ u32 OwnH[512];

    u64* h0w = h0ring + (size_t)g * R0 * 2048;  // [slot][slice 4][512 words]
    u64* h1w = h1ring + (size_t)g * 4 * 2048;
    const int R0m = R0 - 1;

    int peer[3];
    { int c = 0; for (int p = 0; p < 4; ++p) if (p != j) peer[c++] = p; }

    if (L == 0) {
        // ================= layer 0 =================
        half8 wr[2][K0 / 32];
        float bs[2];
#pragma unroll
        for (int tt = 0; tt < 2; ++tt) {
            int t = w + 8 * tt;
            int n = (t >> 2) * 256 + j * 64 + (t & 3) * 16 + col;
            bs[tt] = b0[n];
            const _Float16* wp = wcat0 + (size_t)n * K0 + quad * 8;
#pragma unroll
            for (int kk = 0; kk < K0 / 32; ++kk) wr[tt][kk] = *(const half8*)(wp + kk * 32);
        }
        float cs0 = c0g[(size_t)(c0b + pm) * HID + j * 64 + pu];
        float cs1 = c0g[(size_t)(c0b + pm) * HID + j * 64 + pu + 1];
        {
            int m = tid >> 5, cw = tid & 31;
            const float* hp = h0g + (size_t)(c0b + m) * HID + cw * 8;
            half8 hv;
#pragma unroll
            for (int q2 = 0; q2 < 8; ++q2) hv[q2] = (_Float16)hp[q2];
            *(half8*)&Ash[m * LDA0 + cw * 8] = hv;
            if (cw >= IN_DIM) Ash[m * LDA0 + HID + cw] = (_Float16)0.f;
        }
        const int xm = tid / IN_DIM, xd = tid - xm * IN_DIM;  // for tid<224
        if (tid < 16 * IN_DIM)
            Ash[xm * LDA0 + HID + xd] = (_Float16)x[(size_t)(c0b + xm) * IN_DIM + xd];
        __syncthreads();

        for (int s = 0; s < S_LEN; ++s) {
            // ---- phase1: spec issue + x prefetch + notify poll (wave0)
            float xpre = 0.f;
            if (tid < 16 * IN_DIM && s + 1 < S_LEN)
                xpre = x[((size_t)(s + 1) * BATCH + c0b + xm) * IN_DIM + xd];
            const u64* ap[3];
            u64 vv[3] = {0, 0, 0};
            if (s > 0) {
                const u64* base = h0w + (size_t)((s - 1) & R0m) * 2048;
#pragma unroll
                for (int i = 0; i < 3; ++i) { ap[i] = base + peer[i] * 512 + tid; vv[i] = aload(ap[i]); }
            }
            if (w == 0) {
                bool act = false; const u32* np = nullptr; int tgt = 0;
                if (lane < 24) {
                    act = (s > 0); np = nfy + NFY(0, g, peer[lane >> 3], lane & 7); tgt = s;
                } else if (lane < 28) {
                    act = ((s & 7) == 0) && (s + 2 > R0);
                    np = prog + g * 4 + (lane - 24); tgt = s + 2 - R0;
                }
                bool ok = !act;
                for (;;) {
                    if (!ok) ok = ((int)aload32(np) >= tgt);
                    if (__all(ok)) break;
                    __builtin_amdgcn_s_sleep(1);
                }
            }
            __syncthreads();
            // ---- phase2: validate + gather peers' h0[s-1]
            if (s > 0) {
#pragma unroll
                for (int i = 0; i < 3; ++i) {
                    while ((u32)(vv[i] >> 32) != (u32)s) vv[i] = aload(ap[i]);
                    *(u32*)&Ash[gm * LDA0 + peer[i] * 64 + 2 * gu] = (u32)vv[i];
                }
            }
            __syncthreads();
            // ---- phase3: MFMA + gates + pointwise + publish
            f32x4 acc0 = {bs[0], bs[0], bs[0], bs[0]};
            f32x4 acc1 = {bs[1], bs[1], bs[1], bs[1]};
#pragma unroll
            for (int kk = 0; kk < K0 / 32; ++kk) {
                half8 av = *(const half8*)&Ash[col * LDA0 + kk * 32 + quad * 8];
                acc0 = __builtin_amdgcn_mfma_f32_16x16x32_f16(av, wr[0][kk], acc0, 0, 0, 0);
                acc1 = __builtin_amdgcn_mfma_f32_16x16x32_f16(av, wr[1][kk], acc1, 0, 0, 0);
            }
#pragma unroll
            for (int r = 0; r < 4; ++r) {
                Gsh[(quad * 4 + r) * GST + w * 16 + col] = acc0[r];
                Gsh[(quad * 4 + r) * GST + (w + 8) * 16 + col] = acc1[r];
            }
            __syncthreads();
            {
                float iv = sigf(Gsh[pm * GST + pu]);
                float fv = sigf(Gsh[pm * GST + 64 + pu]);
                float gv = tanhf2(Gsh[pm * GST + 128 + pu]);
                float ov = sigf(Gsh[pm * GST + 192 + pu]);
                cs0 = fv * cs0 + iv * gv;
                float ha = ov * tanhf2(cs0);
                iv = sigf(Gsh[pm * GST + pu + 1]);
                fv = sigf(Gsh[pm * GST + 64 + pu + 1]);
                gv = tanhf2(Gsh[pm * GST + 128 + pu + 1]);
                ov = sigf(Gsh[pm * GST + 192 + pu + 1]);
                cs1 = fv * cs1 + iv * gv;
                float hb = ov * tanhf2(cs1);
                u32 hw = packh2(ha, hb);
                *(u32*)&Ash[pm * LDA0 + j * 64 + pu] = hw;
                astore(h0w + (size_t)(s & R0m) * 2048 + j * 512 + (pm * 32 + iu),
                       (u64)hw | ((u64)(u32)(s + 1) << 32));
            }
            asm volatile("s_waitcnt vmcnt(0)" ::: "memory");
            if (lane == 0) astore32(nfy + NFY(0, g, j, w), (u32)(s + 1));
            if (tid < 16 * IN_DIM && s + 1 < S_LEN)
                Ash[xm * LDA0 + HID + xd] = (_Float16)xpre;
            __syncthreads();
        }
    } else {
        // ================= layer 1 + fused FC =================
        half8 wr[2][K1 / 32];
        float bs[2];
#pragma unroll
        for (int tt = 0; tt < 2; ++tt) {
            int t = w + 8 * tt;
            int n = (t >> 2) * 256 + j * 64 + (t & 3) * 16 + col;
            bs[tt] = b1[n];
            const _Float16* wp = wcat1 + (size_t)n * K1 + quad * 8;
#pragma unroll
            for (int kk = 0; kk < K1 / 32; ++kk) wr[tt][kk] = *(const half8*)(wp + kk * 32);
        }
        for (int i = tid; i < HID; i += 512) WfS[i] = wfc[i];
        const float bfcv = bfc[0];
        float cs0 = c0g[(size_t)(BATCH + c0b + pm) * HID + j * 64 + pu];
        float cs1 = c0g[(size_t)(BATCH + c0b + pm) * HID + j * 64 + pu + 1];
        {
            int m = tid >> 5, cw = tid & 31;
            const float* hp = h0g + (size_t)(BATCH + c0b + m) * HID + cw * 8;
            half8 hv;
#pragma unroll
            for (int q2 = 0; q2 < 8; ++q2) hv[q2] = (_Float16)hp[q2];
            *(half8*)&Ash[m * LDA1 + cw * 8] = hv;
        }
        u32* progself = prog + g * 4 + j;
        // pre-loop speculative issue of h0[0] words
        const u64* hp0[4];
        u64 hv0[4];
#pragma unroll
        for (int p = 0; p < 4; ++p) { hp0[p] = h0w + p * 512 + tid; hv0[p] = aload(hp0[p]); }
        __syncthreads();

        for (int s = 0; s <= S_LEN; ++s) {
            // ---- phase1: spec issue h1 peers + notify poll (wave0) + FC (wave7)
            const u64* ap[3];
            u64 vv[3] = {0, 0, 0};
            if (s > 0) {
                const u64* b1p = h1w + (size_t)((s - 1) & 3) * 2048;
#pragma unroll
                for (int i = 0; i < 3; ++i) { ap[i] = b1p + peer[i] * 512 + tid; vv[i] = aload(ap[i]); }
            }
            if (w == 0) {
                bool act = false; const u32* np = nullptr; int tgt = 0;
                if (lane < 24) {
                    act = (s > 0); np = nfy + NFY(1, g, peer[lane >> 3], lane & 7); tgt = s;
                } else if (lane < 56) {
                    int l2 = lane - 24;
                    act = (s < S_LEN); np = nfy + NFY(0, g, l2 >> 3, l2 & 7); tgt = s + 1;
                }
                bool ok = !act;
                for (;;) {
                    if (!ok) ok = ((int)aload32(np) >= tgt);
                    if (__all(ok)) break;
                    __builtin_amdgcn_s_sleep(1);
                }
            } else if (w == 7 && s >= 2) {
                // FC on h1[s-2] (coherent snapshot in Ash) -> out[s-2]
                int m = 4 * j + quad;
                float fa = 0.f;
#pragma unroll
                for (int k16 = 0; k16 < 16; ++k16) {
                    float hv = (float)Ash[m * LDA1 + col + 16 * k16];
                    fa += fmaxf(hv, 0.f) * WfS[col + 16 * k16];
                }
#pragma unroll
                for (int off = 1; off < 16; off <<= 1) fa += __shfl_xor(fa, off, 16);
                if (col == 0) out[(size_t)(s - 2) * BATCH + c0b + m] = fa + bfcv;
            }
            __syncthreads();
            // ---- phase2: validate + gather h1[s-1] (+own via OwnH) and h0[s]
            if (s > 0) {
#pragma unroll
                for (int i = 0; i < 3; ++i) {
                    while ((u32)(vv[i] >> 32) != (u32)s) vv[i] = aload(ap[i]);
                    *(u32*)&Ash[gm * LDA1 + peer[i] * 64 + 2 * gu] = (u32)vv[i];
                }
                *(u32*)&Ash[gm * LDA1 + j * 64 + 2 * gu] = OwnH[tid];
            }
            if (s < S_LEN) {
#pragma unroll
                for (int p = 0; p < 4; ++p) {
                    while ((u32)(hv0[p] >> 32) != (u32)(s + 1)) hv0[p] = aload(hp0[p]);
                    *(u32*)&Ash[gm * LDA1 + HID + p * 64 + 2 * gu] = (u32)hv0[p];
                }
            }
            __syncthreads();
            if (s == S_LEN) {
                if (w == 7) {  // final FC on h1[S_LEN-1]
                    int m = 4 * j + quad;
                    float fa = 0.f;
#pragma unroll
                    for (int k16 = 0; k16 < 16; ++k16) {
                        float hv = (float)Ash[m * LDA1 + col + 16 * k16];
                        fa += fmaxf(hv, 0.f) * WfS[col + 16 * k16];
                    }
#pragma unroll
                    for (int off = 1; off < 16; off <<= 1) fa += __shfl_xor(fa, off, 16);
                    if (col == 0) out[(size_t)(S_LEN - 1) * BATCH + c0b + m] = fa + bfcv;
                }
                break;
            }
            // ---- phase3: MFMA + gates + pointwise + publish + h0 prefetch
            f32x4 acc0 = {bs[0], bs[0], bs[0], bs[0]};
            f32x4 acc1 = {bs[1], bs[1], bs[1], bs[1]};
#pragma unroll
            for (int kk = 0; kk < K1 / 32; ++kk) {
                half8 av = *(const half8*)&Ash[col * LDA1 + kk * 32 + quad * 8];
                acc0 = __builtin_amdgcn_mfma_f32_16x16x32_f16(av, wr[0][kk], acc0, 0, 0, 0);
                acc1 = __builtin_amdgcn_mfma_f32_16x16x32_f16(av, wr[1][kk], acc1, 0, 0, 0);
            }
#pragma unroll
            for (int r = 0; r < 4; ++r) {
                Gsh[(quad * 4 + r) * GST + w * 16 + col] = acc0[r];
                Gsh[(quad * 4 + r) * GST + (w + 8) * 16 + col] = acc1[r];
            }
            __syncthreads();
            {
                float iv = sigf(Gsh[pm * GST + pu]);
                float fv = sigf(Gsh[pm * GST + 64 + pu]);
                float gv = tanhf2(Gsh[pm * GST + 128 + pu]);
                float ov = sigf(Gsh[pm * GST + 192 + pu]);
                cs0 = fv * cs0 + iv * gv;
                float ha = ov * tanhf2(cs0);
                iv = sigf(Gsh[pm * GST + pu + 1]);
                fv = sigf(Gsh[pm * GST + 64 + pu + 1]);
                gv = tanhf2(Gsh[pm * GST + 128 + pu + 1]);
                ov = sigf(Gsh[pm * GST + 192 + pu + 1]);
                cs1 = fv * cs1 + iv * gv;
                float hb = ov * tanhf2(cs1);
                u32 hw = packh2(ha, hb);
                OwnH[pm * 32 + iu] = hw;   // defer own-slice Ash update (FC snapshot)
                astore(h1w + (size_t)(s & 3) * 2048 + j * 512 + (pm * 32 + iu),
                       (u64)hw | ((u64)(u32)(s + 1) << 32));
            }
            asm volatile("s_waitcnt vmcnt(0)" ::: "memory");
            if (lane == 0) astore32(nfy + NFY(1, g, j, w), (u32)(s + 1));
            // prefetch h0[s+1] (L0 runs ahead; validated next step)
            if (s + 1 < S_LEN) {
#pragma unroll
                for (int p = 0; p < 4; ++p) {
                    hp0[p] = h0w + (size_t)((s + 1) & R0m) * 2048 + p * 512 + tid;
                    hv0[p] = aload(hp0[p]);
                }
            }
            if ((s & 7) == 7 && tid == 0) astore32(progself, (u32)(s + 1));
            __syncthreads();
        }
    }
}

// ---------------------------------------------------------------------------
extern "C" void kernel_launch(void* const* d_in, const int* in_sizes, int n_in,
                              void* d_out, int out_size, void* d_ws, size_t ws_size,
                              hipStream_t stream) {
    const float* x    = (const float*)d_in[0];
    const float* h0   = (const float*)d_in[1];
    const float* c0   = (const float*)d_in[2];
    const float* Wih0 = (const float*)d_in[3];
    const float* Whh0 = (const float*)d_in[4];
    const float* bih0 = (const float*)d_in[5];
    const float* bhh0 = (const float*)d_in[6];
    const float* Wih1 = (const float*)d_in[7];
    const float* Whh1 = (const float*)d_in[8];
    const float* bih1 = (const float*)d_in[9];
    const float* bhh1 = (const float*)d_in[10];
    const float* Wfc  = (const float*)d_in[11];
    const float* bfc  = (const float*)d_in[12];
    float* out = (float*)d_out;

    char* ws = (char*)d_ws;
    constexpr size_t OFF_WCAT0 = 0;
    constexpr size_t SZ_WCAT0 = (size_t)GATES * K0 * 2;   // 576 KB
    constexpr size_t OFF_WCAT1 = OFF_WCAT0 + SZ_WCAT0;
    constexpr size_t SZ_WCAT1 = (size_t)GATES * K1 * 2;   // 1 MB
    constexpr size_t OFF_B0 = OFF_WCAT1 + SZ_WCAT1;
    constexpr size_t OFF_B1 = OFF_B0 + 4096;
    constexpr size_t OFF_PROG = OFF_B1 + 4096;
    constexpr size_t SZ_PROG = 16384;
    constexpr size_t OFF_NFY = OFF_PROG + SZ_PROG;
    constexpr size_t SZ_NFY = 16384;                      // 256 words x 64B pad
    constexpr size_t OFF_H1R = OFF_NFY + SZ_NFY;
    constexpr size_t SZ_H1R = (size_t)4 * 4 * 2048 * 8;   // 256 KB
    constexpr size_t OFF_H0R = OFF_H1R + SZ_H1R;

    _Float16* wcat0 = (_Float16*)(ws + OFF_WCAT0);
    _Float16* wcat1 = (_Float16*)(ws + OFF_WCAT1);
    float* b0 = (float*)(ws + OFF_B0);
    float* b1 = (float*)(ws + OFF_B1);
    u32* prog = (u32*)(ws + OFF_PROG);
    u32* nfy = (u32*)(ws + OFF_NFY);
    u64* h1ring = (u64*)(ws + OFF_H1R);

    int R0 = 128;  // h0 ring slots; per group slot = 16 KB (tagged words)
    while (OFF_H0R + (size_t)4 * R0 * 2048 * 8 > ws_size && R0 > 16) R0 >>= 1;
    u64* h0ring = (u64*)(ws + OFF_H0R);

    hipMemsetAsync(prog, 0, SZ_PROG + SZ_NFY, stream);
    prep_weights<<<256, 256, 0, stream>>>(Wih0, Whh0, bih0, bhh0, Wih1, Whh1, bih1, bhh1,
                                          wcat0, wcat1, b0, b1);
    lstm_scan<<<32, 512, 0, stream>>>(x, h0, c0, wcat0, wcat1, b0, b1, Wfc, bfc,
                                      h0ring, h1ring, nfy, (u32*)prog, out, R0);
}